// Round 3
// baseline (188.891 us; speedup 1.0000x reference)
//
#include <hip/hip_runtime.h>

// ---------------------------------------------------------------------------
// NNSensorResponse: out[s,t] = sum_{b,n} sigmoid(MLPp(x))*MLPa(x)*mask * gauss(t-z)
// B=4,N=8000 (BN=32000), F_IN=3, HID=128, S=1024, T=1024, sigma runtime (=5.0).
// Gaussian is band-limited (sigma=5 -> +-31 ticks ~ 6.2 sigma): bucket electrons
// into 16 buckets of 64-tick granularity; each bucket owns a 128-tick span.
// R3: (a) Gaussian precomputed once into sorted/transposed/padded GT[cg][t][e]
//     (was recomputed 8x per s_tile in k_main: 32.8M exps -> 4.1M in prep);
//     k_main B-frags are direct global 16B loads, GL dropped from LDS.
// (b) ksplit 4->8: 1024 blocks = 4 blocks/CU (was grid-limited to 2).
// (c) k_scan2 parallelized (was 16 lanes x 125 dependent global loads ~30us).
// ---------------------------------------------------------------------------

#define BN_E   32000
#define NBLK   125          // BN_E / 256
#define HIDW   128
#define S_DIM  1024
#define T_DIM  1024
#define NBKT   16
#define KSPL   8
#define MAXPAD (BN_E + NBKT * 31)        // 32496 max padded list length
#define MAXCG  ((MAXPAD + 31) / 32)      // 1016 max 32-electron chunks
#define INV_SQRT_2PI 0.3989422804f

typedef __attribute__((ext_vector_type(8))) unsigned short u16x8;
typedef __attribute__((ext_vector_type(8))) __bf16         bf16x8;
typedef __attribute__((ext_vector_type(4))) float          f32x4;

static __device__ __forceinline__ unsigned short f2bf(float f) {
    union { float f; unsigned int u; } v; v.f = f;
    unsigned int r = v.u + 0x7FFFu + ((v.u >> 16) & 1u);   // RNE, inputs finite
    return (unsigned short)(r >> 16);
}

static __device__ __forceinline__ f32x4 mfma16(u16x8 a, u16x8 b, f32x4 c) {
    return __builtin_amdgcn_mfma_f32_16x16x32_bf16(
        __builtin_bit_cast(bf16x8, a), __builtin_bit_cast(bf16x8, b), c, 0, 0, 0);
}

// ---------------- prep kernels ----------------

// hidden layers for both MLPs, bf16 output. grid: BN_E/2 blocks x 256 thr.
__global__ __launch_bounds__(256) void k_hidden(
    const float* __restrict__ x,
    const float* __restrict__ Wp1, const float* __restrict__ bp1,
    const float* __restrict__ Wa1, const float* __restrict__ ba1,
    unsigned short* __restrict__ HpG, unsigned short* __restrict__ HaG) {
    int e = blockIdx.x * 2 + (threadIdx.x >> 7);
    int j = threadIdx.x & 127;
    float x0 = x[e * 3 + 0], x1 = x[e * 3 + 1], x2 = x[e * 3 + 2];
    float hp = x0 * Wp1[j] + x1 * Wp1[HIDW + j] + x2 * Wp1[2 * HIDW + j] + bp1[j];
    float ha = x0 * Wa1[j] + x1 * Wa1[HIDW + j] + x2 * Wa1[2 * HIDW + j] + ba1[j];
    HpG[e * HIDW + j] = f2bf(fmaxf(hp, 0.f));
    HaG[e * HIDW + j] = f2bf(fmaxf(ha, 0.f));
}

// convert W2 matrices to bf16 (layout preserved [k][s]). grid: 512 x 256.
__global__ __launch_bounds__(256) void k_cvtw(
    const float* __restrict__ Wp2, const float* __restrict__ Wa2,
    unsigned short* __restrict__ Wp2b, unsigned short* __restrict__ Wa2b) {
    int g = blockIdx.x * 256 + threadIdx.x;           // < HIDW*S_DIM
    Wp2b[g] = f2bf(Wp2[g]);
    Wa2b[g] = f2bf(Wa2[g]);
}

static __device__ __forceinline__ int bucket_of(float z) {
    int b = (int)floorf((z - 31.f) * (1.f / 64.f));
    return min(max(b, 0), NBKT - 1);
}

// per-block LDS histogram -> blockCounts[blk][16]. grid: NBLK x 256.
__global__ __launch_bounds__(256) void k_count_blk(const float* __restrict__ z,
                                                   int* __restrict__ bc) {
    __shared__ int h[NBKT];
    if (threadIdx.x < NBKT) h[threadIdx.x] = 0;
    __syncthreads();
    int e = blockIdx.x * 256 + threadIdx.x;           // BN_E % 256 == 0
    atomicAdd(&h[bucket_of(z[e])], 1);
    __syncthreads();
    if (threadIdx.x < NBKT) bc[blockIdx.x * NBKT + threadIdx.x] = h[threadIdx.x];
}

// meta[0..15]=cnt, meta[32..47]=PADDED start (mult of 32), meta[48]=total padded.
// base[blk][b] = intra-bucket offset of block blk. Parallel 2-phase scan:
// thread (seg,b) sums 8 block-entries into regs, 16-step LDS scans, writes back.
__global__ __launch_bounds__(256) void k_scan2(const int* __restrict__ bc,
                                               int* meta, int* __restrict__ base) {
    __shared__ int part[16][16];     // [seg][b]
    __shared__ int segoff[16][16];
    int t = threadIdx.x, b = t & 15, seg = t >> 4;    // 16 segs x 8 blocks
    int v[8]; int sum = 0;
#pragma unroll
    for (int i = 0; i < 8; ++i) {
        int blk = seg * 8 + i;
        v[i] = (blk < NBLK) ? bc[blk * NBKT + b] : 0;
        sum += v[i];
    }
    part[seg][b] = sum;
    __syncthreads();
    if (t < NBKT) {                  // t = bucket
        int run = 0;
        for (int s = 0; s < 16; ++s) { segoff[s][t] = run; run += part[s][t]; }
        meta[t] = run;               // cnt
    }
    __syncthreads();
    if (t == 0) {
        int s = 0;
        for (int i = 0; i < NBKT; ++i) {
            meta[32 + i] = s;
            s += ((meta[i] + 31) >> 5) << 5;          // padded bucket length
        }
        meta[48] = s;
    }
    int run = segoff[seg][b];
#pragma unroll
    for (int i = 0; i < 8; ++i) {
        int blk = seg * 8 + i;
        if (blk < NBLK) { base[blk * NBKT + b] = run; run += v[i]; }
    }
}

// deterministic scatter using LDS ranks into padded list. grid: NBLK x 256.
__global__ __launch_bounds__(256) void k_fill_blk(const float* __restrict__ z,
                                                  const int* __restrict__ meta,
                                                  const int* __restrict__ base,
                                                  int* __restrict__ list) {
    __shared__ int h[NBKT];
    if (threadIdx.x < NBKT) h[threadIdx.x] = 0;
    __syncthreads();
    int e = blockIdx.x * 256 + threadIdx.x;
    int b = bucket_of(z[e]);
    int r = atomicAdd(&h[b], 1);
    list[meta[32 + b] + base[blockIdx.x * NBKT + b] + r] = e;
}

// Gaussian tiles, sorted+transposed: GT[cg*4096 + t_local*32 + e_local] (bf16),
// coef*mask folded in; pad rows zeroed; pad list slots set to 0.
// grid: MAXCG x 256 (one block per 32-electron chunk).
__global__ __launch_bounds__(256) void k_gauss(
    const float* __restrict__ zg, const float* __restrict__ maskg,
    const float* __restrict__ sigp, const int* __restrict__ meta,
    int* __restrict__ list, unsigned short* __restrict__ GT) {
    int cg = blockIdx.x;
    int pos0 = cg * 32;
    if (pos0 >= meta[48]) return;
    int b = 15;
    while (meta[32 + b] > pos0) --b;          // chunk never crosses a bucket
    int tb = b * 64;
    int cnt = meta[b], pstart = meta[32 + b];
    int t = threadIdx.x, e_l = t & 31, tg = t >> 5;
    int pos = pos0 + e_l;
    bool real = (pos - pstart) < cnt;
    int ev = real ? list[pos] : 0;
    if (!real && tg == 0) list[pos] = 0;      // make pad slots safe for H-gather
    float sigma = sigp[0];
    float coef = INV_SQRT_2PI / sigma;
    float nis2 = -1.f / (2.f * sigma * sigma);
    float zz = real ? zg[ev] : 0.f;
    float cm = real ? coef * maskg[ev] : 0.f;
    unsigned short* dst = GT + cg * 4096;
#pragma unroll
    for (int k = 0; k < 16; ++k) {
        int tl = tg * 16 + k;
        float d = (float)(tb + tl) - zz;
        dst[tl * 32 + e_l] = f2bf(cm * __expf(d * d * nis2));
    }
}

// ---------------- main fused kernel ----------------
// grid: (8 s_tiles, 16 buckets, KSPL ksplit), 256 threads (4 waves).
__global__ __launch_bounds__(256, 2) void k_main(
    const unsigned short* __restrict__ HpG, const unsigned short* __restrict__ HaG,
    const unsigned short* __restrict__ Wp2b, const unsigned short* __restrict__ Wa2b,
    const float* __restrict__ bp2, const float* __restrict__ ba2,
    const int* __restrict__ meta, const int* __restrict__ list,
    const unsigned short* __restrict__ GT, float* __restrict__ out) {

    const int s0     = blockIdx.x * 128;
    const int bk     = blockIdx.y;
    const int tb     = bk * 64;                // t span [tb, tb+128)
    const int cnt    = meta[bk];
    const int pstart = meta[32 + bk];          // padded, multiple of 32
    const int nch    = (cnt + 31) >> 5;
    const int per    = (nch + KSPL - 1) / KSPL;
    const int c0     = blockIdx.z * per;
    const int c1     = min(nch, c0 + per);
    if (c0 >= c1) return;                      // uniform across block

    const int tid = threadIdx.x;
    const int w = tid >> 6, l = tid & 63, q = l >> 4, c = l & 15;

    // LDS: H staging (stride 136 shorts) + wave-private Rsp transpose buffer
    __shared__ __align__(16) unsigned short HpL[32 * 136];
    __shared__ __align__(16) unsigned short HaL[32 * 136];
    __shared__ __align__(16) unsigned short RspL[128 * 40];  // [s_local][e]

    // K-invariant W2 fragments, register resident. B-frag: B[k][n=s].
    u16x8 wP[2][4], wA[2][4];
#pragma unroll
    for (int n = 0; n < 2; ++n) {
        int sg = s0 + w * 32 + n * 16 + c;
#pragma unroll
        for (int ks = 0; ks < 4; ++ks) {
            u16x8 vp, va;
#pragma unroll
            for (int j = 0; j < 8; ++j) {
                int k = ks * 32 + q * 8 + j;
                vp[j] = Wp2b[k * S_DIM + sg];
                va[j] = Wa2b[k * S_DIM + sg];
            }
            wP[n][ks] = vp; wA[n][ks] = va;
        }
    }
    float bp2v[2] = { bp2[s0 + w * 32 + c], bp2[s0 + w * 32 + 16 + c] };
    float ba2v[2] = { ba2[s0 + w * 32 + c], ba2[s0 + w * 32 + 16 + c] };

    const f32x4 z4 = { 0.f, 0.f, 0.f, 0.f };
    f32x4 acc2[2][8];
#pragma unroll
    for (int m = 0; m < 2; ++m)
#pragma unroll
        for (int n8 = 0; n8 < 8; ++n8) acc2[m][n8] = z4;

    const unsigned short* gt0 = GT + (size_t)(pstart >> 5) * 4096;

    for (int ci = c0; ci < c1; ++ci) {
        __syncthreads();
        {   // stage Hp/Ha chunk: 32 electrons x 128 k (bf16), gather via list
            int e = tid >> 3, part = tid & 7;
            int ev = list[pstart + ci * 32 + e];          // pads are 0 (safe)
            const uint4* sp = (const uint4*)&HpG[ev * HIDW + part * 16];
            const uint4* sa = (const uint4*)&HaG[ev * HIDW + part * 16];
            uint4* dp = (uint4*)&HpL[e * 136 + part * 16];
            uint4* da = (uint4*)&HaL[e * 136 + part * 16];
            dp[0] = sp[0]; dp[1] = sp[1];
            da[0] = sa[0]; da[1] = sa[1];
        }
        __syncthreads();

        // GEMM1: C1[e][s] = Hp/Ha[e][k] @ W2[k][s]  (M=e 32, N=s 32/wave, K=128)
        f32x4 aP[2][2], aA[2][2];
#pragma unroll
        for (int m = 0; m < 2; ++m)
#pragma unroll
            for (int n = 0; n < 2; ++n) { aP[m][n] = z4; aA[m][n] = z4; }
#pragma unroll
        for (int ks = 0; ks < 4; ++ks) {
            u16x8 hp0 = *(const u16x8*)&HpL[(c)      * 136 + ks * 32 + q * 8];
            u16x8 hp1 = *(const u16x8*)&HpL[(c + 16) * 136 + ks * 32 + q * 8];
            u16x8 ha0 = *(const u16x8*)&HaL[(c)      * 136 + ks * 32 + q * 8];
            u16x8 ha1 = *(const u16x8*)&HaL[(c + 16) * 136 + ks * 32 + q * 8];
#pragma unroll
            for (int n = 0; n < 2; ++n) {
                aP[0][n] = mfma16(hp0, wP[n][ks], aP[0][n]);
                aP[1][n] = mfma16(hp1, wP[n][ks], aP[1][n]);
                aA[0][n] = mfma16(ha0, wA[n][ks], aA[0][n]);
                aA[1][n] = mfma16(ha1, wA[n][ks], aA[1][n]);
            }
        }

        // epilogue1: rsp = sigmoid(p+bp2)*(a+ba2); C-layout -> RspL[s][e]
        // (rows are wave-private -> no barrier needed around RspL)
#pragma unroll
        for (int m = 0; m < 2; ++m)
#pragma unroll
            for (int n = 0; n < 2; ++n) {
                f32x4 p = aP[m][n], a = aA[m][n];
                unsigned long long pk = 0;
#pragma unroll
                for (int r = 0; r < 4; ++r) {
                    float pr = p[r] + bp2v[n];
                    float ar = a[r] + ba2v[n];
                    float sg = __builtin_amdgcn_rcpf(1.f + __expf(-pr));
                    pk |= (unsigned long long)f2bf(sg * ar) << (16 * r);
                }
                int sl = w * 32 + n * 16 + c;        // col of C1 = s
                int e0 = m * 16 + q * 4;             // row of C1 = e
                *(unsigned long long*)&RspL[sl * 40 + e0] = pk;
            }

        // GEMM2: out[s][t] += Rsp[s][e] @ G[e][t]  (M=s 32/wave, N=t 128, K=32)
        // B-frags read directly from precomputed GT (global, L2-resident)
        const unsigned short* gt = gt0 + ci * 4096;
        u16x8 bfr[8];
#pragma unroll
        for (int n8 = 0; n8 < 8; ++n8)
            bfr[n8] = *(const u16x8*)&gt[(n8 * 16 + c) * 32 + q * 8];
#pragma unroll
        for (int m = 0; m < 2; ++m) {
            u16x8 afr = *(const u16x8*)&RspL[(w * 32 + m * 16 + c) * 40 + q * 8];
#pragma unroll
            for (int n8 = 0; n8 < 8; ++n8)
                acc2[m][n8] = mfma16(afr, bfr[n8], acc2[m][n8]);
        }
    }

    // epilogue2: atomic accumulate into out (bucket spans overlap + ksplit)
#pragma unroll
    for (int m = 0; m < 2; ++m)
#pragma unroll
        for (int n8 = 0; n8 < 8; ++n8) {
            int t = tb + n8 * 16 + c;
            if (t < T_DIM) {
                int srow = s0 + w * 32 + m * 16 + q * 4;
#pragma unroll
                for (int r = 0; r < 4; ++r)
                    atomicAdd(&out[(srow + r) * T_DIM + t], acc2[m][n8][r]);
            }
        }
}

// ---------------- launch ----------------

extern "C" void kernel_launch(void* const* d_in, const int* in_sizes, int n_in,
                              void* d_out, int out_size, void* d_ws, size_t ws_size,
                              hipStream_t stream) {
    const float* x    = (const float*)d_in[0];
    const float* zp   = (const float*)d_in[1];
    const float* mask = (const float*)d_in[2];
    const float* Wp1  = (const float*)d_in[3];
    const float* bp1  = (const float*)d_in[4];
    const float* Wp2  = (const float*)d_in[5];
    const float* bp2  = (const float*)d_in[6];
    const float* Wa1  = (const float*)d_in[7];
    const float* ba1  = (const float*)d_in[8];
    const float* Wa2  = (const float*)d_in[9];
    const float* ba2  = (const float*)d_in[10];
    const float* sig  = (const float*)d_in[11];

    char* ws = (char*)d_ws;
    unsigned short* HpG  = (unsigned short*)(ws);                      //  8,192,000 B
    unsigned short* HaG  = (unsigned short*)(ws + 8192000);            //  8,192,000 B
    unsigned short* Wp2b = (unsigned short*)(ws + 16384000);           //    262,144 B
    unsigned short* Wa2b = (unsigned short*)(ws + 16646144);           //    262,144 B
    int*            meta = (int*)(ws + 16908288);                      //        256 B
    int*            list = (int*)(ws + 16908544);                      //    130,048 B (padded)
    int*            bc   = (int*)(ws + 17038592);                      //      8,000 B
    int*            base = (int*)(ws + 17046592);                      //      8,000 B
    unsigned short* GT   = (unsigned short*)(ws + 17054592);           //  8,323,072 B
    // total ws: ~25.4 MB

    hipMemsetAsync(d_out, 0, (size_t)S_DIM * T_DIM * sizeof(float), stream);

    k_hidden<<<BN_E / 2, 256, 0, stream>>>(x, Wp1, bp1, Wa1, ba1, HpG, HaG);
    k_cvtw<<<(HIDW * S_DIM) / 256, 256, 0, stream>>>(Wp2, Wa2, Wp2b, Wa2b);
    k_count_blk<<<NBLK, 256, 0, stream>>>(zp, bc);
    k_scan2<<<1, 256, 0, stream>>>(bc, meta, base);
    k_fill_blk<<<NBLK, 256, 0, stream>>>(zp, meta, base, list);
    k_gauss<<<MAXCG, 256, 0, stream>>>(zp, mask, sig, meta, list, GT);

    k_main<<<dim3(8, NBKT, KSPL), 256, 0, stream>>>(
        HpG, HaG, Wp2b, Wa2b, bp2, ba2, meta, list, GT, (float*)d_out);
}